// Round 2
// baseline (59.567 us; speedup 1.0000x reference)
//
#include <hip/hip_runtime.h>

#define NF 256          // NUM_NEURONS
#define NK 64           // NUM_KNOTS (cp rows)
#define FPB 64          // features per block
#define RPB 16          // rows per block (was 32) -> 1024 blocks, 4 waves/SIMD

// out[b,f] = sum_{r=0..3} N_r(x[b,f]) * cp[i-3+r, f] + bias[f]
// i = interval (t[i] <= x < t[i+1]) = ji + 6, ji = floor(x*55).
// Knot vector (68 entries) is piecewise linear in index k:
//   k<=5:      t = 0.0005k - 0.0035
//   6<=k<=61:  t = (k-6)/55
//   k>=62:     t = 0.0005(k-62) + 1.001
// De Boor DENOMINATORS are compile-time constants except at ji in
// {0,1,53,54}; all occurring values:
//   1/55 -> 55, 2/55 -> 27.5, 3/55 -> 55/3
//   1/55+0.001   -> 52.13270142,  1/55+0.0015 -> 50.80831409,
//   2/55+0.001   -> 26.76399027
// -> constant-select instead of v_rcp (verified round 1, absmax 0.03125).

__global__ __launch_bounds__(256, 4) void bspline_kernel(
    const float* __restrict__ x,
    const float* __restrict__ cp,     // (64, 256) row-major
    const float* __restrict__ bias,   // (256,)
    float* __restrict__ out)
{
    __shared__ float4 cpl4[NK * FPB / 4];         // 16 KiB: (k, ff) slab
    float* cpl = reinterpret_cast<float*>(cpl4);

    const int tid  = threadIdx.x;
    const int ff   = tid & (FPB - 1);             // feature offset in group
    const int rsub = tid >> 6;                    // 0..3 row sub-lane
    const int fg   = blockIdx.x & 3;              // feature group (0..3)
    const int rg   = blockIdx.x >> 2;             // row group
    const int f0   = fg * FPB;
    const int r0   = rg * RPB;

    // ---- prefetch x into registers (overlaps staging + barrier) ----
    const float* xp = x + (r0 + rsub) * NF + f0 + ff;
    float xv[4];
#pragma unroll
    for (int it = 0; it < 4; ++it)
        xv[it] = xp[it * 4 * NF];

    // ---- stage this block's 64-feature slab of cp ----
    {
        const float4* cp4 = reinterpret_cast<const float4*>(cp);
        const int fb4 = f0 >> 2;                  // float4 col base (features/4)
#pragma unroll
        for (int s = 0; s < 4; ++s) {
            const int idx = tid + 256 * s;        // 0..1023
            const int k   = idx >> 4;             // knot row 0..63
            const int c4  = idx & 15;             // float4 col in slab
            cpl4[idx] = cp4[k * (NF / 4) + fb4 + c4];
        }
    }
    const float bv = bias[f0 + ff];
    __syncthreads();

    constexpr float inv55 = 1.0f / 55.0f;
    // exact reciprocal-denominator constants (derived in f64, rounded to f32)
    constexpr float RD2I = 27.5f;              // 55/2
    constexpr float RD3I = 18.33333333f;       // 55/3
    constexpr float RD_A = 52.13270142f;       // 1/(1/55 + 0.001)
    constexpr float RD_B = 50.80831409f;       // 1/(1/55 + 0.0015)
    constexpr float RD_C = 26.76399027f;       // 1/(2/55 + 0.001)

#pragma unroll
    for (int it = 0; it < 4; ++it) {
        const float xx = xv[it];

        float jf = floorf(xx * 55.0f);
        jf = fminf(fmaxf(jf, 0.0f), 54.0f);       // v_med3 clamp
        const int ji = (int)jf;

        // knots t[i-2..i+3]
        const float t_im2 = fmaxf(fmaf(jf, 5e-4f, -1.5e-3f), (jf - 2.0f) * inv55);
        const float t_im1 = fmaxf(fmaf(jf, 5e-4f, -1.0e-3f), (jf - 1.0f) * inv55);
        const float t_i   = jf * inv55;
        const float t_ip1 = (jf + 1.0f) * inv55;
        const float t_ip2 = fminf((jf + 2.0f) * inv55, fmaf(jf, 5e-4f, 0.974f));
        const float t_ip3 = fminf((jf + 3.0f) * inv55, fmaf(jf, 5e-4f, 0.9745f));

        const float l1 = xx - t_i,   r1 = t_ip1 - xx;
        const float l2 = xx - t_im1, r2 = t_ip2 - xx;
        const float l3 = xx - t_im2, r3 = t_ip3 - xx;

        // constant-select reciprocal denominators (no v_rcp)
        const bool j0  = (ji == 0),  j1  = (ji == 1);
        const bool j53 = (ji == 53), j54 = (ji == 54);
        const float rd21 = j0  ? RD_A : RD2I;
        const float rd22 = j54 ? RD_A : RD2I;
        const float rd31 = j0  ? RD_B : (j1  ? RD_C : RD3I);
        const float rd32 = (j0 || j54) ? RD_C : RD3I;
        const float rd33 = j54 ? RD_B : (j53 ? RD_C : RD3I);

        // de Boor basis (A2.2), division-free
        float temp = 55.0f;                        // rd11 (exact)
        float N0 = r1 * temp;
        float N1 = l1 * temp;
        temp = N0 * rd21; N0 = r1 * temp; float saved = l2 * temp;
        temp = N1 * rd22; N1 = fmaf(r2, temp, saved); float N2 = l1 * temp;
        temp = N0 * rd31; N0 = r1 * temp; saved = l3 * temp;
        temp = N1 * rd32; N1 = fmaf(r2, temp, saved); saved = l2 * temp;
        temp = N2 * rd33; N2 = fmaf(r3, temp, saved); const float N3 = l1 * temp;

        // LDS gather: rows ji+3..ji+6 of the slab; bank = lane&31 -> free
        const float* c = &cpl[(ji + 3) * FPB + ff];
        float acc = fmaf(N0, c[0 * FPB], bv);
        acc = fmaf(N1, c[1 * FPB], acc);
        acc = fmaf(N2, c[2 * FPB], acc);
        acc = fmaf(N3, c[3 * FPB], acc);

        out[(r0 + rsub + it * 4) * NF + f0 + ff] = acc;
    }
}

extern "C" void kernel_launch(void* const* d_in, const int* in_sizes, int n_in,
                              void* d_out, int out_size, void* d_ws, size_t ws_size,
                              hipStream_t stream) {
    const float* x    = (const float*)d_in[0];   // (4096, 256)
    const float* cp   = (const float*)d_in[1];   // (64, 256)
    const float* bias = (const float*)d_in[2];   // (256,)
    float* out = (float*)d_out;

    const int batch = in_sizes[0] / NF;          // 4096
    const int grid = (batch / RPB) * (NF / FPB); // 256 * 4 = 1024 blocks
    bspline_kernel<<<grid, 256, 0, stream>>>(x, cp, bias, out);
}

// Round 3
// 59.131 us; speedup vs baseline: 1.0074x; 1.0074x over previous
//
#include <hip/hip_runtime.h>

#define NF 256          // NUM_NEURONS
#define NK 64           // NUM_KNOTS (cp rows)
#define FPB 64          // features per block
#define RPB 16          // rows per block -> 1024 blocks, 4 blocks/CU

// out[b,f] = sum_{r=0..3} N_r(x[b,f]) * cp[i-3+r, f] + bias[f]
// i = interval (t[i] <= x < t[i+1]) = ji + 6, ji = floor(x*55).
// Knot vector (68 entries) is piecewise linear in index k:
//   k<=5:      t = 0.0005k - 0.0035
//   6<=k<=61:  t = (k-6)/55
//   k>=62:     t = 0.0005(k-62) + 1.001
// De Boor DENOMINATORS are compile-time constants except at ji in
// {0,1,53,54}; occurring values:
//   1/55 -> 55, 2/55 -> 27.5, 3/55 -> 55/3
//   1/55+0.001 -> 52.13270142, 1/55+0.0015 -> 50.80831409,
//   2/55+0.001 -> 26.76399027
// -> constant-select instead of v_rcp (verified, absmax 0.03125).
// This round: cp staging via global_load_lds DMA (16B/lane, wave-uniform
// LDS base + lane*16 -> legal pattern); __syncthreads drains vmcnt(0).

typedef const __attribute__((address_space(1))) unsigned int global_u32;
typedef __attribute__((address_space(3))) unsigned int lds_u32;

__global__ __launch_bounds__(256, 4) void bspline_kernel(
    const float* __restrict__ x,
    const float* __restrict__ cp,     // (64, 256) row-major
    const float* __restrict__ bias,   // (256,)
    float* __restrict__ out)
{
    __shared__ float4 cpl4[NK * FPB / 4];         // 16 KiB: (k, ff) slab
    float* cpl = reinterpret_cast<float*>(cpl4);

    const int tid  = threadIdx.x;
    const int ff   = tid & (FPB - 1);             // feature offset in group
    const int rsub = tid >> 6;                    // 0..3 row sub-lane
    const int fg   = blockIdx.x & 3;              // feature group (0..3)
    const int rg   = blockIdx.x >> 2;             // row group
    const int f0   = fg * FPB;
    const int r0   = rg * RPB;

    // ---- async stage this block's 64-feature slab of cp (DMA to LDS) ----
    {
        const float4* cp4 = reinterpret_cast<const float4*>(cp);
        const int fb4 = f0 >> 2;                  // float4 col base
#pragma unroll
        for (int s = 0; s < 4; ++s) {
            const int idx = tid + 256 * s;        // 0..1023
            const int k   = idx >> 4;             // knot row 0..63
            const int c4  = idx & 15;             // float4 col in slab
            __builtin_amdgcn_global_load_lds(
                (global_u32*)(cp4 + (k * (NF / 4) + fb4 + c4)),
                (lds_u32*)(cpl4 + idx),
                16, 0, 0);
        }
    }

    // ---- prefetch x into registers (overlaps DMA in flight) ----
    const float* xp = x + (r0 + rsub) * NF + f0 + ff;
    float xv[4];
#pragma unroll
    for (int it = 0; it < 4; ++it)
        xv[it] = xp[it * 4 * NF];

    const float bv = bias[f0 + ff];
    __syncthreads();                              // waits vmcnt(0): DMA done

    constexpr float inv55 = 1.0f / 55.0f;
    // exact reciprocal-denominator constants (derived in f64)
    constexpr float RD2I = 27.5f;              // 55/2
    constexpr float RD3I = 18.33333333f;       // 55/3
    constexpr float RD_A = 52.13270142f;       // 1/(1/55 + 0.001)
    constexpr float RD_B = 50.80831409f;       // 1/(1/55 + 0.0015)
    constexpr float RD_C = 26.76399027f;       // 1/(2/55 + 0.001)

#pragma unroll
    for (int it = 0; it < 4; ++it) {
        const float xx = xv[it];

        float jf = floorf(xx * 55.0f);
        jf = fminf(fmaxf(jf, 0.0f), 54.0f);       // v_med3 clamp
        const int ji = (int)jf;

        // knots t[i-2..i+3]
        const float t_im2 = fmaxf(fmaf(jf, 5e-4f, -1.5e-3f), (jf - 2.0f) * inv55);
        const float t_im1 = fmaxf(fmaf(jf, 5e-4f, -1.0e-3f), (jf - 1.0f) * inv55);
        const float t_i   = jf * inv55;
        const float t_ip1 = (jf + 1.0f) * inv55;
        const float t_ip2 = fminf((jf + 2.0f) * inv55, fmaf(jf, 5e-4f, 0.974f));
        const float t_ip3 = fminf((jf + 3.0f) * inv55, fmaf(jf, 5e-4f, 0.9745f));

        const float l1 = xx - t_i,   r1 = t_ip1 - xx;
        const float l2 = xx - t_im1, r2 = t_ip2 - xx;
        const float l3 = xx - t_im2, r3 = t_ip3 - xx;

        // constant-select reciprocal denominators (no v_rcp)
        const bool j0  = (ji == 0),  j1  = (ji == 1);
        const bool j53 = (ji == 53), j54 = (ji == 54);
        const float rd21 = j0  ? RD_A : RD2I;
        const float rd22 = j54 ? RD_A : RD2I;
        const float rd31 = j0  ? RD_B : (j1  ? RD_C : RD3I);
        const float rd32 = (j0 || j54) ? RD_C : RD3I;
        const float rd33 = j54 ? RD_B : (j53 ? RD_C : RD3I);

        // de Boor basis (A2.2), division-free
        float temp = 55.0f;                        // rd11 (exact)
        float N0 = r1 * temp;
        float N1 = l1 * temp;
        temp = N0 * rd21; N0 = r1 * temp; float saved = l2 * temp;
        temp = N1 * rd22; N1 = fmaf(r2, temp, saved); float N2 = l1 * temp;
        temp = N0 * rd31; N0 = r1 * temp; saved = l3 * temp;
        temp = N1 * rd32; N1 = fmaf(r2, temp, saved); saved = l2 * temp;
        temp = N2 * rd33; N2 = fmaf(r3, temp, saved); const float N3 = l1 * temp;

        // LDS gather: rows ji+3..ji+6 of the slab; bank = lane&31 -> free
        const float* c = &cpl[(ji + 3) * FPB + ff];
        float acc = fmaf(N0, c[0 * FPB], bv);
        acc = fmaf(N1, c[1 * FPB], acc);
        acc = fmaf(N2, c[2 * FPB], acc);
        acc = fmaf(N3, c[3 * FPB], acc);

        out[(r0 + rsub + it * 4) * NF + f0 + ff] = acc;
    }
}

extern "C" void kernel_launch(void* const* d_in, const int* in_sizes, int n_in,
                              void* d_out, int out_size, void* d_ws, size_t ws_size,
                              hipStream_t stream) {
    const float* x    = (const float*)d_in[0];   // (4096, 256)
    const float* cp   = (const float*)d_in[1];   // (64, 256)
    const float* bias = (const float*)d_in[2];   // (256,)
    float* out = (float*)d_out;

    const int batch = in_sizes[0] / NF;          // 4096
    const int grid = (batch / RPB) * (NF / FPB); // 256 * 4 = 1024 blocks
    bspline_kernel<<<grid, 256, 0, stream>>>(x, cp, bias, out);
}